// Round 11
// baseline (199.675 us; speedup 1.0000x reference)
//
#include <hip/hip_runtime.h>
#include <hip/hip_bf16.h>

#define N_ 16
#define D_ 2048
#define H_ 32
#define W_ 32
#define HW_ 1024
#define F_ 512

typedef unsigned short u16;
typedef unsigned int u32;
typedef __attribute__((ext_vector_type(8))) short bf16x8;
typedef __attribute__((ext_vector_type(4))) float f32x4;

__device__ __forceinline__ u16 f2bf(float f) {
  union { float fv; u32 u; } c; c.fv = f;
  u32 u = c.u;
  u32 r = (u + 0x7fffu + ((u >> 16) & 1u)) >> 16;   // RNE
  return (u16)r;
}

#define GLD_LDS16(gp, lp) __builtin_amdgcn_global_load_lds( \
    (const __attribute__((address_space(1))) void*)(gp), \
    (__attribute__((address_space(3))) void*)(lp), 16, 0, 0)

// ---- K0: zero sumsq (64 KB) ----
__global__ __launch_bounds__(256) void k_zero(float* __restrict__ p) {
  int i = blockIdx.x * 256 + threadIdx.x;   // 16 blocks x 256 x float4 = 64 KB
  ((float4*)p)[i] = (float4){0.f, 0.f, 0.f, 0.f};
}

// ---- K1: sum of squares over channel dim -> sumsq[n][hw] (atomic partials) ----
__global__ __launch_bounds__(256) void k_sumsq(const float* __restrict__ x, float* __restrict__ sumsq) {
  const int n = blockIdx.x;        // 16
  const int dc = blockIdx.y;       // 32 chunks x 64 d
  const int t = threadIdx.x;
  const float* xp = x + ((size_t)n * D_ + (size_t)dc * 64) * HW_;
  float s0 = 0.f, s1 = 0.f, s2 = 0.f, s3 = 0.f;
  for (int d = 0; d < 64; ++d) {
    const float* row = xp + (size_t)d * HW_;
    float v0 = row[t], v1 = row[t + 256], v2 = row[t + 512], v3 = row[t + 768];
    s0 += v0 * v0; s1 += v1 * v1; s2 += v2 * v2; s3 += v3 * v3;
  }
  atomicAdd(&sumsq[n * HW_ + t      ], s0);
  atomicAdd(&sumsq[n * HW_ + t + 256], s1);
  atomicAdd(&sumsq[n * HW_ + t + 512], s2);
  atomicAdd(&sumsq[n * HW_ + t + 768], s3);
}

// ---- K2: halo-free rolling-window 3x3 box + GeM, packed-A output ----
// grid (n=16, dc=32), block 256: w = t&31, g = t>>5 (8 d's per thread).
// Streams h=0..31 with a 2-value hs carry per d; every x row read exactly once.
// GeM accumulated at load; gbuf plain-stored (one block per (n,d)).
__global__ __launch_bounds__(256) void k_box2(const float* __restrict__ x,
    const float* __restrict__ sumsq, const float* __restrict__ pvec,
    float* __restrict__ gbuf, u16* __restrict__ packA) {
  const int n = blockIdx.x, dc = blockIdx.y;
  const int d0 = dc * 64;
  const int t = threadIdx.x;
  const int w = t & 31, g = t >> 5;
  const float p = pvec[0];
  const bool p3 = (p == 3.0f);

  __shared__ __align__(16) u16 sbox[128 * 68];   // [128 hw][64 d pad->68] per 4-h strip

  const float* xb = x + ((size_t)(n * D_ + d0 + g * 8)) * HW_ + w;
  const float* sq = sumsq + n * HW_ + w;

  float hc0[8], hc1[8], s[8];
  // preamble: row 0
  {
    float rn0 = 1.0f / fmaxf(sqrtf(sq[0]), 1e-12f);
    #pragma unroll
    for (int j = 0; j < 8; ++j) {
      float v = xb[(size_t)j * HW_] * rn0;
      float cv = fmaxf(v, 1e-6f);
      s[j] = p3 ? cv * cv * cv : __powf(cv, p);
      float l = __shfl_up(v, 1, 32), r = __shfl_down(v, 1, 32);
      if (w == 0) l = 0.f;
      if (w == 31) r = 0.f;
      hc0[j] = 0.f;          // hs[-1]
      hc1[j] = l + v + r;    // hs[0]
    }
  }

  for (int ht = 0; ht < 8; ++ht) {
    const int h0 = ht * 4;
    float rnr[4];
    #pragma unroll
    for (int q = 0; q < 4; ++q) {
      int hp = h0 + 1 + q;
      rnr[q] = (hp < H_) ? 1.0f / fmaxf(sqrtf(sq[hp * W_]), 1e-12f) : 0.f;
    }
    #pragma unroll
    for (int j = 0; j < 8; ++j) {
      float hsq[4];
      #pragma unroll
      for (int q = 0; q < 4; ++q) {
        int hp = h0 + 1 + q;
        float v = 0.f;
        if (hp < H_) {
          v = xb[(size_t)j * HW_ + hp * W_] * rnr[q];
          float cv = fmaxf(v, 1e-6f);
          s[j] += p3 ? cv * cv * cv : __powf(cv, p);
        }
        float l = __shfl_up(v, 1, 32), r = __shfl_down(v, 1, 32);
        if (w == 0) l = 0.f;
        if (w == 31) r = 0.f;
        hsq[q] = l + v + r;
      }
      // box rows h0..h0+3 from hs window [hc0, hc1, hsq0..3]
      u16* sb = sbox + (g * 8 + j);
      sb[(0 * 32 + w) * 68] = f2bf(hc0[j] + hc1[j] + hsq[0]);
      sb[(1 * 32 + w) * 68] = f2bf(hc1[j] + hsq[0] + hsq[1]);
      sb[(2 * 32 + w) * 68] = f2bf(hsq[0] + hsq[1] + hsq[2]);
      sb[(3 * 32 + w) * 68] = f2bf(hsq[1] + hsq[2] + hsq[3]);
      hc0[j] = hsq[2];       // hs[h0+3]
      hc1[j] = hsq[3];       // hs[h0+4]
    }
    __syncthreads();
    // packed writeout: thread -> 32 bf16 of one hw row = frags (kt, hi=0..3)
    {
      const int r = t >> 1, half = t & 1;
      const u16* srcp = sbox + r * 68 + half * 32;
      uint2 a[8];
      #pragma unroll
      for (int q = 0; q < 8; ++q) a[q] = *(const uint2*)(srcp + q * 4);
      const int mt = n * 16 + ht * 2 + (r >> 6);
      const int mf = (r >> 4) & 3, r15 = r & 15;
      const int kt = dc * 2 + half;
      u16* dst = packA + ((size_t)(mt * 64 + kt) * 4 + mf) * 512 + r15 * 8;
      #pragma unroll
      for (int q = 0; q < 4; ++q) {      // q = hi
        uint4 b;
        b.x = a[2 * q].x; b.y = a[2 * q].y; b.z = a[2 * q + 1].x; b.w = a[2 * q + 1].y;
        *(uint4*)(dst + q * 128) = b;
      }
    }
    __syncthreads();
  }

  // GeM reduce over 32 w-lanes; plain store (exactly one block per (n,d))
  #pragma unroll
  for (int j = 0; j < 8; ++j) {
    float v = s[j];
    v += __shfl_xor(v, 16, 32);
    v += __shfl_xor(v, 8, 32);
    v += __shfl_xor(v, 4, 32);
    v += __shfl_xor(v, 2, 32);
    v += __shfl_xor(v, 1, 32);
    if (w == 0) gbuf[n * D_ + d0 + g * 8 + j] = v;
  }
}

// ---- K3: proj_w fp32 -> bf16, fragment-packed: packB[wq][kt][nf][lane][8] ----
__global__ __launch_bounds__(256) void k_wconv(const float* __restrict__ w, u16* __restrict__ packB) {
  const int i = blockIdx.x * 256 + threadIdx.x;   // 0..131071
  const int lane = i & 63, nf = (i >> 6) & 3, kt = (i >> 8) & 63, wq = i >> 14;  // wq 0..7
  const int r15 = lane & 15, hi = lane >> 4;
  const int f = wq * 64 + nf * 16 + r15;
  const int k = kt * 32 + hi * 8;
  const float* src = w + (size_t)f * D_ + k;
  float4 v0 = *(const float4*)(src);
  float4 v1 = *(const float4*)(src + 4);
  u16 r[8] = { f2bf(v0.x), f2bf(v0.y), f2bf(v0.z), f2bf(v0.w),
               f2bf(v1.x), f2bf(v1.y), f2bf(v1.z), f2bf(v1.w) };
  *(uint4*)(packB + (size_t)i * 8) = *(const uint4*)r;
}

// ---- K4: GEMM [64 hw] x [512 f] x [K 2048], packed operands, B lead-2 ----
// Per step kt: [load B(kt+2) to regs] -> vmcnt -> s_barrier -> [stage A(kt+5)
// via global_load_lds, 8 bufs] -> ds_read + MFMA(kt). Triple-buffered B regs
// give B two full step-times of latency budget (contended-L2 theory); A gets
// three (in-order coupling). vmcnt counts derived from the retirement queue.
__global__ __launch_bounds__(512) void k_gemm(const u16* __restrict__ packA,
    const u16* __restrict__ packB, const float* __restrict__ bias,
    float* __restrict__ outL) {
  const int n  = blockIdx.x >> 4;
  const int mtl = blockIdx.x & 15;
  const int mt = blockIdx.x;            // global 64-row tile index
  const int hw0 = mtl * 64;
  const int t = threadIdx.x;
  const int lane = t & 63, wv = t >> 6;
  const int r15 = lane & 15, hi = lane >> 4;

  __shared__ __align__(16) float smem_f[128 * 68];   // 34.8 KB; A bufs alias first 32 KB
  __shared__ float s_sq[8][64];
  __shared__ float s_rn[64];

  f32x4 acc[4][4];
  #pragma unroll
  for (int a = 0; a < 4; ++a)
    #pragma unroll
    for (int b = 0; b < 4; ++b) acc[a][b] = (f32x4){0.f, 0.f, 0.f, 0.f};

  // A stage source: contiguous 1KB per (kt, mf-chunk); wave stages chunk (wv&3)
  const u16* asrc = packA + ((size_t)(mt * 64) * 4 + (wv & 3)) * 512 + lane * 8;
  // B fragments: contiguous 1KB each; wave owns f-quad wv
  const u16* bbase = packB + (size_t)wv * 131072 + lane * 8;

#define STAGE_A(KT) GLD_LDS16(asrc + (size_t)(KT) * 2048, \
    (char*)smem_f + ((KT) & 7) * 4096 + (wv & 3) * 1024)

  // prologue: B(0), B(1) first, then A(0..4)
  bf16x8 bc[4], bn[4], bn2[4];
  #pragma unroll
  for (int nf = 0; nf < 4; ++nf) bc[nf] = *(const bf16x8*)(bbase + nf * 512);
  #pragma unroll
  for (int nf = 0; nf < 4; ++nf) bn[nf] = *(const bf16x8*)(bbase + (4 + nf) * 512);
  __builtin_amdgcn_sched_barrier(0);
  #pragma unroll
  for (int q = 0; q < 5; ++q) STAGE_A(q);
  __builtin_amdgcn_sched_barrier(0);

  for (int kt = 0; kt < 64; ++kt) {
    // pre-barrier: B(kt+2) loads (2-step lead)
    if (kt + 2 < 64) {
      #pragma unroll
      for (int nf = 0; nf < 4; ++nf)
        bn2[nf] = *(const bf16x8*)(bbase + ((kt + 2) * 4 + nf) * 512);
    }
    __builtin_amdgcn_sched_barrier(0);
    if (kt == 0) {
      asm volatile("s_waitcnt vmcnt(8)" ::: "memory");
    } else if (kt == 1) {
      asm volatile("s_waitcnt vmcnt(12)" ::: "memory");
    } else if (kt < 60) {
      asm volatile("s_waitcnt vmcnt(10)" ::: "memory");  // retire B(kt)+A(..kt+2)
    } else if (kt == 60) {
      asm volatile("s_waitcnt vmcnt(9)" ::: "memory");
    } else if (kt == 61) {
      asm volatile("s_waitcnt vmcnt(8)" ::: "memory");
    } else if (kt == 62) {
      asm volatile("s_waitcnt vmcnt(4)" ::: "memory");
    } else {
      asm volatile("s_waitcnt vmcnt(0)" ::: "memory");
    }
    __builtin_amdgcn_sched_barrier(0);
    __builtin_amdgcn_s_barrier();                         // A tile kt visible to all waves
    __builtin_amdgcn_sched_barrier(0);
    // post-barrier: A-stage 5 ahead (8 bufs; WAR-safe)
    if (kt <= 58) STAGE_A(kt + 5);
    __builtin_amdgcn_sched_barrier(0);

    const u16* sA = (const u16*)((const char*)smem_f + (kt & 7) * 4096);
    bf16x8 af[4];
    #pragma unroll
    for (int mf = 0; mf < 4; ++mf)
      af[mf] = *(const bf16x8*)(sA + mf * 512 + lane * 8);
    #pragma unroll
    for (int mf = 0; mf < 4; ++mf)
      #pragma unroll
      for (int nf = 0; nf < 4; ++nf)
        acc[mf][nf] = __builtin_amdgcn_mfma_f32_16x16x32_bf16(af[mf], bc[nf], acc[mf][nf], 0, 0, 0);
    #pragma unroll
    for (int nf = 0; nf < 4; ++nf) { bc[nf] = bn[nf]; bn[nf] = bn2[nf]; }
  }
#undef STAGE_A

  // epilogue: bias, per-row (hw) l2 norm over all 512 f, transposed store
  float badd[4];
  #pragma unroll
  for (int nf = 0; nf < 4; ++nf) badd[nf] = bias[wv * 64 + nf * 16 + r15];
  #pragma unroll
  for (int mf = 0; mf < 4; ++mf)
    #pragma unroll
    for (int nf = 0; nf < 4; ++nf)
      #pragma unroll
      for (int j = 0; j < 4; ++j) acc[mf][nf][j] += badd[nf];

  #pragma unroll
  for (int mf = 0; mf < 4; ++mf)
    #pragma unroll
    for (int j = 0; j < 4; ++j) {
      float s = 0.f;
      #pragma unroll
      for (int nf = 0; nf < 4; ++nf) { float v = acc[mf][nf][j]; s += v * v; }
      s += __shfl_xor(s, 1); s += __shfl_xor(s, 2); s += __shfl_xor(s, 4); s += __shfl_xor(s, 8);
      if ((lane & 15) == 0) s_sq[wv][mf * 16 + hi * 4 + j] = s;
    }
  __syncthreads();
  if (t < 64) {
    float s = 0.f;
    #pragma unroll
    for (int w8 = 0; w8 < 8; ++w8) s += s_sq[w8][t];
    s_rn[t] = 1.0f / fmaxf(sqrtf(s), 1e-12f);
  }
  __syncthreads();

  float* ct = smem_f;   // [128 f-rows][68] fp32
  for (int nf = 0; nf < 4; ++nf) {
    const int fi = wv * 16 + r15;
    #pragma unroll
    for (int mf = 0; mf < 4; ++mf)
      #pragma unroll
      for (int j = 0; j < 4; ++j) {
        int m = mf * 16 + hi * 4 + j;
        ct[fi * 68 + m] = acc[mf][nf][j] * s_rn[m];
      }
    __syncthreads();
    {
      int fr = t >> 2, mq = t & 3;
      int f = (fr >> 4) * 64 + nf * 16 + (fr & 15);
      float* dst = outL + ((size_t)(n * F_ + f)) * HW_ + hw0 + mq * 16;
      const float* srcp = ct + fr * 68 + mq * 16;
      float4 a0 = *(const float4*)(srcp);
      float4 a1 = *(const float4*)(srcp + 4);
      float4 a2 = *(const float4*)(srcp + 8);
      float4 a3 = *(const float4*)(srcp + 12);
      *(float4*)(dst) = a0; *(float4*)(dst + 4) = a1;
      *(float4*)(dst + 8) = a2; *(float4*)(dst + 12) = a3;
    }
    __syncthreads();
  }
}

// ---- K5: GeM finalize: gg = (gbuf/1024)^(1/p) ----
__global__ __launch_bounds__(256) void k_gem_fin(const float* __restrict__ gbuf,
    const float* __restrict__ pvec, float* __restrict__ gg) {
  int i = blockIdx.x * 256 + threadIdx.x;
  float p = pvec[0];
  float m = gbuf[i] * (1.0f / 1024.0f);
  gg[i] = (p == 3.0f) ? cbrtf(m) : powf(m, 1.0f / p);
}

// ---- K6: gproj[n][f] = dot(gg[n], W[f]) + b[f] ----
__global__ __launch_bounds__(256) void k_gproj(const float* __restrict__ w,
    const float* __restrict__ bias, const float* __restrict__ gg,
    float* __restrict__ gproj) {
  const int f = blockIdx.x;
  const int t = threadIdx.x;
  float wreg[8];
  #pragma unroll
  for (int j = 0; j < 8; ++j) wreg[j] = w[(size_t)f * D_ + t + j * 256];
  __shared__ float red[4];
  const int lane = t & 63, wv = t >> 6;
  for (int n = 0; n < N_; ++n) {
    float s = 0.f;
    #pragma unroll
    for (int j = 0; j < 8; ++j) s += wreg[j] * gg[n * D_ + t + j * 256];
    #pragma unroll
    for (int off = 32; off >= 1; off >>= 1) s += __shfl_down(s, off);
    if (lane == 0) red[wv] = s;
    __syncthreads();
    if (t == 0) gproj[n * F_ + f] = red[0] + red[1] + red[2] + red[3] + bias[f];
    __syncthreads();
  }
}

// ---- K7: l2norm g rows -> d_out[0:8192] ----
__global__ __launch_bounds__(512) void k_gnorm(const float* __restrict__ gproj, float* __restrict__ outg) {
  const int n = blockIdx.x;
  const int t = threadIdx.x;
  float v = gproj[n * F_ + t];
  float s = v * v;
  const int lane = t & 63, wv = t >> 6;
  #pragma unroll
  for (int off = 32; off >= 1; off >>= 1) s += __shfl_down(s, off);
  __shared__ float red[8];
  __shared__ float rtot;
  if (lane == 0) red[wv] = s;
  __syncthreads();
  if (t == 0) {
    float a = 0.f;
    #pragma unroll
    for (int i = 0; i < 8; ++i) a += red[i];
    rtot = 1.0f / fmaxf(sqrtf(a), 1e-12f);
  }
  __syncthreads();
  outg[n * F_ + t] = v * rtot;
}

extern "C" void kernel_launch(void* const* d_in, const int* in_sizes, int n_in,
                              void* d_out, int out_size, void* d_ws, size_t ws_size,
                              hipStream_t stream) {
  const float* x  = (const float*)d_in[0];
  const float* pw = (const float*)d_in[1];
  const float* pb = (const float*)d_in[2];
  const float* pv = (const float*)d_in[3];
  float* out = (float*)d_out;

  char* ws = (char*)d_ws;
  float* sumsq = (float*)ws;                                   // 64 KB
  float* gbuf  = (float*)(ws + 65536);                         // 128 KB (plain-stored, no zero)
  float* gg    = (float*)(ws + 65536 + 131072);                // 128 KB
  float* gproj = (float*)(ws + 65536 + 2 * 131072);            // 32 KB
  u16*   packB = (u16*)(ws + 65536 + 2 * 131072 + 32768);      // 2 MiB
  u16*   packA = (u16*)(ws + 4u * 1024u * 1024u);              // 64 MiB

  k_zero<<<dim3(16), dim3(256), 0, stream>>>(sumsq);           // sumsq only
  k_sumsq<<<dim3(16, 32), dim3(256), 0, stream>>>(x, sumsq);
  k_wconv<<<dim3(512), dim3(256), 0, stream>>>(pw, packB);
  k_box2<<<dim3(16, 32), dim3(256), 0, stream>>>(x, sumsq, pv, gbuf, packA);
  k_gem_fin<<<dim3(128), dim3(256), 0, stream>>>(gbuf, pv, gg);
  k_gproj<<<dim3(512), dim3(256), 0, stream>>>(pw, pb, gg, gproj);
  k_gnorm<<<dim3(16), dim3(512), 0, stream>>>(gproj, out);
  k_gemm<<<dim3(256), dim3(512), 0, stream>>>(packA, packB, pb, out + N_ * F_);
}

// Round 12
// 195.123 us; speedup vs baseline: 1.0233x; 1.0233x over previous
//
#include <hip/hip_runtime.h>
#include <hip/hip_bf16.h>

#define N_ 16
#define D_ 2048
#define H_ 32
#define W_ 32
#define HW_ 1024
#define F_ 512

typedef unsigned short u16;
typedef unsigned int u32;
typedef __attribute__((ext_vector_type(8))) short bf16x8;
typedef __attribute__((ext_vector_type(4))) float f32x4;

__device__ __forceinline__ u16 f2bf(float f) {
  union { float fv; u32 u; } c; c.fv = f;
  u32 u = c.u;
  u32 r = (u + 0x7fffu + ((u >> 16) & 1u)) >> 16;   // RNE
  return (u16)r;
}

#define GLD_LDS16(gp, lp) __builtin_amdgcn_global_load_lds( \
    (const __attribute__((address_space(1))) void*)(gp), \
    (__attribute__((address_space(3))) void*)(lp), 16, 0, 0)

// ---- K0: zero sumsq+gbuf (192 KB contiguous) ----
__global__ __launch_bounds__(256) void k_zero(float* __restrict__ p) {
  int i = blockIdx.x * 256 + threadIdx.x;
  ((float4*)p)[i] = (float4){0.f, 0.f, 0.f, 0.f};
}

// ---- K1: sum of squares over channel dim -> sumsq[n][hw] (atomic partials) ----
__global__ __launch_bounds__(256) void k_sumsq(const float* __restrict__ x, float* __restrict__ sumsq) {
  const int n = blockIdx.x;        // 16
  const int dc = blockIdx.y;       // 32 chunks x 64 d
  const int t = threadIdx.x;
  const float* xp = x + ((size_t)n * D_ + (size_t)dc * 64) * HW_;
  float s0 = 0.f, s1 = 0.f, s2 = 0.f, s3 = 0.f;
  for (int d = 0; d < 64; ++d) {
    const float* row = xp + (size_t)d * HW_;
    float v0 = row[t], v1 = row[t + 256], v2 = row[t + 512], v3 = row[t + 768];
    s0 += v0 * v0; s1 += v1 * v1; s2 += v2 * v2; s3 += v3 * v3;
  }
  atomicAdd(&sumsq[n * HW_ + t      ], s0);
  atomicAdd(&sumsq[n * HW_ + t + 256], s1);
  atomicAdd(&sumsq[n * HW_ + t + 512], s2);
  atomicAdd(&sumsq[n * HW_ + t + 768], s3);
}

// ---- K2: register-resident separable 3x3 box + GeM partials (r8 form) ----
// grid (n=16, ht=8, dc=32); block 256. packA[mt128][kt][mf 0..7][lane][8] u16.
__global__ __launch_bounds__(256) void k_box2(const float* __restrict__ x,
    const float* __restrict__ sumsq, const float* __restrict__ pvec,
    float* __restrict__ gbuf, u16* __restrict__ packA) {
  const int n = blockIdx.x, ht = blockIdx.y, dc = blockIdx.z;
  const int h0 = ht * 4, d0 = dc * 64;
  const int t = threadIdx.x;
  const int w = t & 31, g = t >> 5;
  const float p = pvec[0];
  const bool p3 = (p == 3.0f);

  __shared__ __align__(16) u16 sbox[128 * 68];   // [hw 128][d 64 pad->68]

  float rn[6];
  #pragma unroll
  for (int jj = 0; jj < 6; ++jj) {
    int hp = h0 - 1 + jj;
    float r = 0.f;
    if (hp >= 0 && hp < H_) r = 1.0f / fmaxf(sqrtf(sumsq[n * HW_ + hp * W_ + w]), 1e-12f);
    rn[jj] = r;
  }

  float s[8];
  #pragma unroll
  for (int j = 0; j < 8; ++j) s[j] = 0.f;

  #pragma unroll 2
  for (int j = 0; j < 8; ++j) {
    const int d = d0 + g * 8 + j;
    const float* col = x + ((size_t)(n * D_ + d)) * HW_ + w;
    float v[6];
    #pragma unroll
    for (int jj = 0; jj < 6; ++jj) {
      int hp = h0 - 1 + jj;
      float xv = (hp >= 0 && hp < H_) ? col[hp * W_] : 0.f;
      v[jj] = xv * rn[jj];
    }
    #pragma unroll
    for (int jj = 1; jj <= 4; ++jj) {
      float cv = fmaxf(v[jj], 1e-6f);
      s[j] += p3 ? cv * cv * cv : __powf(cv, p);
    }
    float hs[6];
    #pragma unroll
    for (int jj = 0; jj < 6; ++jj) {
      float l = __shfl_up(v[jj], 1, 32);
      float r = __shfl_down(v[jj], 1, 32);
      if (w == 0) l = 0.f;
      if (w == 31) r = 0.f;
      hs[jj] = l + v[jj] + r;
    }
    #pragma unroll
    for (int k = 0; k < 4; ++k) {
      float b = hs[k] + hs[k + 1] + hs[k + 2];
      sbox[(k * 32 + w) * 68 + g * 8 + j] = f2bf(b);
    }
  }
  __syncthreads();

  // packed writeout for 128-row tiles: mt = n*8+ht, row r = t>>1 (0..127)
  {
    const int r = t >> 1, half = t & 1;
    const u16* srcp = sbox + r * 68 + half * 32;
    uint2 a[8];
    #pragma unroll
    for (int q = 0; q < 8; ++q) a[q] = *(const uint2*)(srcp + q * 4);
    const int mt = n * 8 + ht;
    const int mf = r >> 4, r15 = r & 15;
    const int kt = dc * 2 + half;
    u16* dst = packA + (((size_t)mt * 64 + kt) * 8 + mf) * 512 + r15 * 8;
    #pragma unroll
    for (int q = 0; q < 4; ++q) {        // q = hi
      uint4 b;
      b.x = a[2 * q].x; b.y = a[2 * q].y; b.z = a[2 * q + 1].x; b.w = a[2 * q + 1].y;
      *(uint4*)(dst + q * 128) = b;
    }
  }

  #pragma unroll
  for (int j = 0; j < 8; ++j) {
    float v = s[j];
    v += __shfl_xor(v, 16, 32);
    v += __shfl_xor(v, 8, 32);
    v += __shfl_xor(v, 4, 32);
    v += __shfl_xor(v, 2, 32);
    v += __shfl_xor(v, 1, 32);
    if (w == 0) atomicAdd(&gbuf[n * D_ + d0 + g * 8 + j], v);
  }
}

// ---- K3: proj_w fp32 -> bf16, fragment-packed: packB[wq][kt][nf][lane][8] ----
__global__ __launch_bounds__(256) void k_wconv(const float* __restrict__ w, u16* __restrict__ packB) {
  const int i = blockIdx.x * 256 + threadIdx.x;   // 0..131071
  const int lane = i & 63, nf = (i >> 6) & 3, kt = (i >> 8) & 63, wq = i >> 14;  // wq 0..7
  const int r15 = lane & 15, hi = lane >> 4;
  const int f = wq * 64 + nf * 16 + r15;
  const int k = kt * 32 + hi * 8;
  const float* src = w + (size_t)f * D_ + k;
  float4 v0 = *(const float4*)(src);
  float4 v1 = *(const float4*)(src + 4);
  u16 r[8] = { f2bf(v0.x), f2bf(v0.y), f2bf(v0.z), f2bf(v0.w),
               f2bf(v1.x), f2bf(v1.y), f2bf(v1.z), f2bf(v1.w) };
  *(uint4*)(packB + (size_t)i * 8) = *(const uint4*)r;
}

// ---- K4: GEMM, M=128 x F=512 per block (128 blocks), A+B both LDS-staged ----
// Per step: A 8KB + B 32KB = 40 chunks of 1KB; each of 8 waves stages exactly
// 5 chunks (1 A + 4 B of its f-quad) -> uniform 5 vm-ops/wave/step. 3 bufs
// (120KB). Loop: vmcnt(5) -> s_barrier -> stage(kt+2) -> MFMA(kt).
// B L2-traffic halves vs 64-row tiles (each B byte feeds 128 output rows).
__global__ __launch_bounds__(512) void k_gemm(const u16* __restrict__ packA,
    const u16* __restrict__ packB, const float* __restrict__ bias,
    float* __restrict__ outL) {
  const int mt = blockIdx.x;            // 0..127
  const int n  = mt >> 3;
  const int hw0 = (mt & 7) * 128;
  const int t = threadIdx.x;
  const int lane = t & 63, wv = t >> 6;
  const int r15 = lane & 15, hi = lane >> 4;

  __shared__ __align__(16) u16 smem[3 * 20480];   // 3 bufs x (A 4096 + B 16384) u16 = 120 KB
  __shared__ float s_sq[8][128];
  __shared__ float s_rn[128];

  f32x4 acc[8][4];
  #pragma unroll
  for (int a = 0; a < 8; ++a)
    #pragma unroll
    for (int b = 0; b < 4; ++b) acc[a][b] = (f32x4){0.f, 0.f, 0.f, 0.f};

  const u16* asrc = packA + ((size_t)mt * 64 * 8 + wv) * 512 + lane * 8;     // +kt*4096
  const u16* bsrc = packB + (size_t)wv * 131072 + lane * 8;                  // +(kt*4+q)*512

#define STAGE(KT) do {                                                     \
    u16* dst_ = smem + ((KT) % 3) * 20480;                                 \
    GLD_LDS16(asrc + (size_t)(KT) * 4096, (char*)(dst_ + wv * 512));       \
    _Pragma("unroll")                                                      \
    for (int q = 0; q < 4; ++q)                                            \
      GLD_LDS16(bsrc + ((size_t)(KT) * 4 + q) * 512,                       \
                (char*)(dst_ + 4096 + (wv * 4 + q) * 512));                \
  } while (0)

  STAGE(0);
  STAGE(1);

  for (int kt = 0; kt < 64; ++kt) {
    __builtin_amdgcn_sched_barrier(0);
    if (kt < 63) {
      asm volatile("s_waitcnt vmcnt(5)" ::: "memory");   // tile kt retired; kt+1 in flight
    } else {
      asm volatile("s_waitcnt vmcnt(0)" ::: "memory");
    }
    __builtin_amdgcn_sched_barrier(0);
    __builtin_amdgcn_s_barrier();                         // tile kt visible to all waves
    __builtin_amdgcn_sched_barrier(0);
    if (kt <= 61) STAGE(kt + 2);                          // WAR-safe: buf (kt-1)%3 done pre-barrier
    __builtin_amdgcn_sched_barrier(0);

    const u16* sA = smem + (kt % 3) * 20480;
    const u16* sB = sA + 4096;
    bf16x8 af[8], bf[4];
    #pragma unroll
    for (int mf = 0; mf < 8; ++mf)
      af[mf] = *(const bf16x8*)(sA + mf * 512 + lane * 8);
    #pragma unroll
    for (int nf = 0; nf < 4; ++nf)
      bf[nf] = *(const bf16x8*)(sB + (wv * 4 + nf) * 512 + lane * 8);
    #pragma unroll
    for (int mf = 0; mf < 8; ++mf)
      #pragma unroll
      for (int nf = 0; nf < 4; ++nf)
        acc[mf][nf] = __builtin_amdgcn_mfma_f32_16x16x32_bf16(af[mf], bf[nf], acc[mf][nf], 0, 0, 0);
  }
#undef STAGE

  // epilogue: bias, per-row (hw) l2 norm over all 512 f, transposed store
  float badd[4];
  #pragma unroll
  for (int nf = 0; nf < 4; ++nf) badd[nf] = bias[wv * 64 + nf * 16 + r15];
  #pragma unroll
  for (int mf = 0; mf < 8; ++mf)
    #pragma unroll
    for (int nf = 0; nf < 4; ++nf)
      #pragma unroll
      for (int j = 0; j < 4; ++j) acc[mf][nf][j] += badd[nf];

  #pragma unroll
  for (int mf = 0; mf < 8; ++mf)
    #pragma unroll
    for (int j = 0; j < 4; ++j) {
      float s = 0.f;
      #pragma unroll
      for (int nf = 0; nf < 4; ++nf) { float v = acc[mf][nf][j]; s += v * v; }
      s += __shfl_xor(s, 1); s += __shfl_xor(s, 2); s += __shfl_xor(s, 4); s += __shfl_xor(s, 8);
      if (r15 == 0) s_sq[wv][mf * 16 + hi * 4 + j] = s;
    }
  __syncthreads();
  if (t < 128) {
    float s = 0.f;
    #pragma unroll
    for (int w8 = 0; w8 < 8; ++w8) s += s_sq[w8][t];
    s_rn[t] = 1.0f / fmaxf(sqrtf(s), 1e-12f);
  }
  __syncthreads();

  float* ct = (float*)smem;   // [128 f-rows][132 hw] fp32 = 67.6 KB (aliases staging)
  for (int nf = 0; nf < 4; ++nf) {
    const int fi = wv * 16 + r15;
    #pragma unroll
    for (int mf = 0; mf < 8; ++mf)
      #pragma unroll
      for (int j = 0; j < 4; ++j) {
        int m = mf * 16 + hi * 4 + j;
        ct[fi * 132 + m] = acc[mf][nf][j] * s_rn[m];
      }
    __syncthreads();
    {
      int fr = t >> 2, mq = t & 3;                       // fr 0..127, mq 0..3
      int f = (fr >> 4) * 64 + nf * 16 + (fr & 15);
      float* dst = outL + ((size_t)(n * F_ + f)) * HW_ + hw0 + mq * 32;
      const float* srcp = ct + fr * 132 + mq * 32;
      #pragma unroll
      for (int q = 0; q < 8; ++q)
        ((float4*)dst)[q] = ((const float4*)srcp)[q];
    }
    __syncthreads();
  }
}

// ---- K5: GeM finalize: gg = (gbuf/1024)^(1/p) ----
__global__ __launch_bounds__(256) void k_gem_fin(const float* __restrict__ gbuf,
    const float* __restrict__ pvec, float* __restrict__ gg) {
  int i = blockIdx.x * 256 + threadIdx.x;
  float p = pvec[0];
  float m = gbuf[i] * (1.0f / 1024.0f);
  gg[i] = (p == 3.0f) ? cbrtf(m) : powf(m, 1.0f / p);
}

// ---- K6: gproj[n][f] = dot(gg[n], W[f]) + b[f] ----
__global__ __launch_bounds__(256) void k_gproj(const float* __restrict__ w,
    const float* __restrict__ bias, const float* __restrict__ gg,
    float* __restrict__ gproj) {
  const int f = blockIdx.x;
  const int t = threadIdx.x;
  float wreg[8];
  #pragma unroll
  for (int j = 0; j < 8; ++j) wreg[j] = w[(size_t)f * D_ + t + j * 256];
  __shared__ float red[4];
  const int lane = t & 63, wv = t >> 6;
  for (int n = 0; n < N_; ++n) {
    float s = 0.f;
    #pragma unroll
    for (int j = 0; j < 8; ++j) s += wreg[j] * gg[n * D_ + t + j * 256];
    #pragma unroll
    for (int off = 32; off >= 1; off >>= 1) s += __shfl_down(s, off);
    if (lane == 0) red[wv] = s;
    __syncthreads();
    if (t == 0) gproj[n * F_ + f] = red[0] + red[1] + red[2] + red[3] + bias[f];
    __syncthreads();
  }
}

// ---- K7: l2norm g rows -> d_out[0:8192] ----
__global__ __launch_bounds__(512) void k_gnorm(const float* __restrict__ gproj, float* __restrict__ outg) {
  const int n = blockIdx.x;
  const int t = threadIdx.x;
  float v = gproj[n * F_ + t];
  float s = v * v;
  const int lane = t & 63, wv = t >> 6;
  #pragma unroll
  for (int off = 32; off >= 1; off >>= 1) s += __shfl_down(s, off);
  __shared__ float red[8];
  __shared__ float rtot;
  if (lane == 0) red[wv] = s;
  __syncthreads();
  if (t == 0) {
    float a = 0.f;
    #pragma unroll
    for (int i = 0; i < 8; ++i) a += red[i];
    rtot = 1.0f / fmaxf(sqrtf(a), 1e-12f);
  }
  __syncthreads();
  outg[n * F_ + t] = v * rtot;
}

extern "C" void kernel_launch(void* const* d_in, const int* in_sizes, int n_in,
                              void* d_out, int out_size, void* d_ws, size_t ws_size,
                              hipStream_t stream) {
  const float* x  = (const float*)d_in[0];
  const float* pw = (const float*)d_in[1];
  const float* pb = (const float*)d_in[2];
  const float* pv = (const float*)d_in[3];
  float* out = (float*)d_out;

  char* ws = (char*)d_ws;
  float* sumsq = (float*)ws;                                   // 64 KB
  float* gbuf  = (float*)(ws + 65536);                         // 128 KB
  float* gg    = (float*)(ws + 65536 + 131072);                // 128 KB
  float* gproj = (float*)(ws + 65536 + 2 * 131072);            // 32 KB
  u16*   packB = (u16*)(ws + 65536 + 2 * 131072 + 32768);      // 2 MiB
  u16*   packA = (u16*)(ws + 4u * 1024u * 1024u);              // 64 MiB

  k_zero<<<dim3(48), dim3(256), 0, stream>>>(sumsq);           // sumsq + gbuf
  k_sumsq<<<dim3(16, 32), dim3(256), 0, stream>>>(x, sumsq);
  k_wconv<<<dim3(512), dim3(256), 0, stream>>>(pw, packB);
  k_box2<<<dim3(16, 8, 32), dim3(256), 0, stream>>>(x, sumsq, pv, gbuf, packA);
  k_gem_fin<<<dim3(128), dim3(256), 0, stream>>>(gbuf, pv, gg);
  k_gproj<<<dim3(512), dim3(256), 0, stream>>>(pw, pb, gg, gproj);
  k_gnorm<<<dim3(16), dim3(512), 0, stream>>>(gproj, out);
  k_gemm<<<dim3(128), dim3(512), 0, stream>>>(packA, packB, pb, out + N_ * F_);
}

// Round 13
// 139.784 us; speedup vs baseline: 1.4285x; 1.3959x over previous
//
#include <hip/hip_runtime.h>
#include <hip/hip_bf16.h>

#define N_ 16
#define D_ 2048
#define H_ 32
#define W_ 32
#define HW_ 1024
#define F_ 512

typedef unsigned short u16;
typedef unsigned int u32;
typedef __attribute__((ext_vector_type(8))) short bf16x8;
typedef __attribute__((ext_vector_type(4))) float f32x4;

__device__ __forceinline__ u16 f2bf(float f) {
  union { float fv; u32 u; } c; c.fv = f;
  u32 u = c.u;
  u32 r = (u + 0x7fffu + ((u >> 16) & 1u)) >> 16;   // RNE
  return (u16)r;
}

#define GLD_LDS16(gp, lp) __builtin_amdgcn_global_load_lds( \
    (const __attribute__((address_space(1))) void*)(gp), \
    (__attribute__((address_space(3))) void*)(lp), 16, 0, 0)

// ---- K0: zero sumsq+gbuf (192 KB contiguous) ----
__global__ __launch_bounds__(256) void k_zero(float* __restrict__ p) {
  int i = blockIdx.x * 256 + threadIdx.x;
  ((float4*)p)[i] = (float4){0.f, 0.f, 0.f, 0.f};
}

// ---- K1: sum of squares over channel dim -> sumsq[n][hw] (atomic partials) ----
__global__ __launch_bounds__(256) void k_sumsq(const float* __restrict__ x, float* __restrict__ sumsq) {
  const int n = blockIdx.x;        // 16
  const int dc = blockIdx.y;       // 32 chunks x 64 d
  const int t = threadIdx.x;
  const float* xp = x + ((size_t)n * D_ + (size_t)dc * 64) * HW_;
  float s0 = 0.f, s1 = 0.f, s2 = 0.f, s3 = 0.f;
  for (int d = 0; d < 64; ++d) {
    const float* row = xp + (size_t)d * HW_;
    float v0 = row[t], v1 = row[t + 256], v2 = row[t + 512], v3 = row[t + 768];
    s0 += v0 * v0; s1 += v1 * v1; s2 += v2 * v2; s3 += v3 * v3;
  }
  atomicAdd(&sumsq[n * HW_ + t      ], s0);
  atomicAdd(&sumsq[n * HW_ + t + 256], s1);
  atomicAdd(&sumsq[n * HW_ + t + 512], s2);
  atomicAdd(&sumsq[n * HW_ + t + 768], s3);
}

// ---- K2: float4-vectorized separable 3x3 box + GeM partials ----
// grid (n=16, ht=8, dc=32) — UNCHANGED topology (16 blocks/CU), 17 KB LDS.
// thread: w4 = t&7 (w-quad), dg = t>>3 (d-pair). 12 float4 x-loads/thread
// (was 48 scalar dwords). Output: r8 packed-A layout.
__global__ __launch_bounds__(256) void k_box2(const float* __restrict__ x,
    const float* __restrict__ sumsq, const float* __restrict__ pvec,
    float* __restrict__ gbuf, u16* __restrict__ packA) {
  const int n = blockIdx.x, ht = blockIdx.y, dc = blockIdx.z;
  const int h0 = ht * 4, d0 = dc * 64;
  const int t = threadIdx.x;
  const int w4 = t & 7, dg = t >> 3;
  const int wq = w4 * 4;
  const float p = pvec[0];
  const bool p3 = (p == 3.0f);

  __shared__ __align__(16) u16 sbox[128 * 68];   // [hw 128][d 64 pad->68]
  __shared__ __align__(16) float rnl[6][32];

  if (t < 192) {
    int jj = t >> 5, w = t & 31;
    int hp = h0 - 1 + jj;
    float r = 0.f;
    if (hp >= 0 && hp < H_) r = 1.0f / fmaxf(sqrtf(sumsq[n * HW_ + hp * W_ + w]), 1e-12f);
    rnl[jj][w] = r;
  }
  __syncthreads();

  float s0 = 0.f, s1 = 0.f;
  #pragma unroll
  for (int dj = 0; dj < 2; ++dj) {
    const int d = d0 + dg * 2 + dj;
    const float* base = x + ((size_t)(n * D_ + d)) * HW_ + wq;
    float4 v[6];
    #pragma unroll
    for (int jj = 0; jj < 6; ++jj) {
      int hp = h0 - 1 + jj;
      if (hp >= 0 && hp < H_) {
        float4 xv = *(const float4*)(base + hp * W_);
        float4 rr = *(const float4*)(&rnl[jj][wq]);
        v[jj].x = xv.x * rr.x; v[jj].y = xv.y * rr.y;
        v[jj].z = xv.z * rr.z; v[jj].w = xv.w * rr.w;
      } else {
        v[jj] = (float4){0.f, 0.f, 0.f, 0.f};
      }
    }
    // GeM partial over the 4 owned rows (jj=1..4 <-> h0..h0+3)
    float g = 0.f;
    #pragma unroll
    for (int jj = 1; jj <= 4; ++jj) {
      float cx = fmaxf(v[jj].x, 1e-6f), cy = fmaxf(v[jj].y, 1e-6f);
      float cz = fmaxf(v[jj].z, 1e-6f), cw = fmaxf(v[jj].w, 1e-6f);
      if (p3) g += cx * cx * cx + cy * cy * cy + cz * cz * cz + cw * cw * cw;
      else    g += __powf(cx, p) + __powf(cy, p) + __powf(cz, p) + __powf(cw, p);
    }
    if (dj == 0) s0 = g; else s1 = g;
    // horizontal 3-tap within 8-lane w4 groups
    #pragma unroll
    for (int jj = 0; jj < 6; ++jj) {
      float lf = __shfl_up(v[jj].w, 1, 8);
      float rf = __shfl_down(v[jj].x, 1, 8);
      if (w4 == 0) lf = 0.f;
      if (w4 == 7) rf = 0.f;
      float4 h;
      h.x = lf + v[jj].x + v[jj].y;
      h.y = v[jj].x + v[jj].y + v[jj].z;
      h.z = v[jj].y + v[jj].z + v[jj].w;
      h.w = v[jj].z + v[jj].w + rf;
      v[jj] = h;
    }
    // vertical 3-tap + transposed LDS stage
    #pragma unroll
    for (int k = 0; k < 4; ++k) {
      float4 b;
      b.x = v[k].x + v[k + 1].x + v[k + 2].x;
      b.y = v[k].y + v[k + 1].y + v[k + 2].y;
      b.z = v[k].z + v[k + 1].z + v[k + 2].z;
      b.w = v[k].w + v[k + 1].w + v[k + 2].w;
      const int rb = k * 32 + wq;
      sbox[(rb + 0) * 68 + dg * 2 + dj] = f2bf(b.x);
      sbox[(rb + 1) * 68 + dg * 2 + dj] = f2bf(b.y);
      sbox[(rb + 2) * 68 + dg * 2 + dj] = f2bf(b.z);
      sbox[(rb + 3) * 68 + dg * 2 + dj] = f2bf(b.w);
    }
  }
  __syncthreads();

  // packed writeout (r8 layout): thread -> 32 bf16 of one hw row
  {
    const int r = t >> 1, half = t & 1;
    const u16* srcp = sbox + r * 68 + half * 32;
    uint2 a[8];
    #pragma unroll
    for (int q = 0; q < 8; ++q) a[q] = *(const uint2*)(srcp + q * 4);
    const int mt = n * 16 + ht * 2 + (r >> 6);
    const int mf = (r >> 4) & 3, r15 = r & 15;
    const int kt = dc * 2 + half;
    u16* dst = packA + ((size_t)(mt * 64 + kt) * 4 + mf) * 512 + r15 * 8;
    #pragma unroll
    for (int q = 0; q < 4; ++q) {        // q = hi
      uint4 b;
      b.x = a[2 * q].x; b.y = a[2 * q].y; b.z = a[2 * q + 1].x; b.w = a[2 * q + 1].y;
      *(uint4*)(dst + q * 128) = b;
    }
  }

  // GeM reduce over the 8 w4-lanes
  {
    float v0 = s0, v1 = s1;
    v0 += __shfl_xor(v0, 1, 8); v1 += __shfl_xor(v1, 1, 8);
    v0 += __shfl_xor(v0, 2, 8); v1 += __shfl_xor(v1, 2, 8);
    v0 += __shfl_xor(v0, 4, 8); v1 += __shfl_xor(v1, 4, 8);
    if (w4 == 0) {
      atomicAdd(&gbuf[n * D_ + d0 + dg * 2    ], v0);
      atomicAdd(&gbuf[n * D_ + d0 + dg * 2 + 1], v1);
    }
  }
}

// ---- K3: proj_w fp32 -> bf16, fragment-packed: packB[wq][kt][nf][lane][8] ----
__global__ __launch_bounds__(256) void k_wconv(const float* __restrict__ w, u16* __restrict__ packB) {
  const int i = blockIdx.x * 256 + threadIdx.x;   // 0..131071
  const int lane = i & 63, nf = (i >> 6) & 3, kt = (i >> 8) & 63, wq = i >> 14;  // wq 0..7
  const int r15 = lane & 15, hi = lane >> 4;
  const int f = wq * 64 + nf * 16 + r15;
  const int k = kt * 32 + hi * 8;
  const float* src = w + (size_t)f * D_ + k;
  float4 v0 = *(const float4*)(src);
  float4 v1 = *(const float4*)(src + 4);
  u16 r[8] = { f2bf(v0.x), f2bf(v0.y), f2bf(v0.z), f2bf(v0.w),
               f2bf(v1.x), f2bf(v1.y), f2bf(v1.z), f2bf(v1.w) };
  *(uint4*)(packB + (size_t)i * 8) = *(const uint4*)r;
}

// ---- K4: GEMM [64 hw] x [512 f] x [K 2048] (r8 form, best measured) ----
// 4-buf A via global_load_lds, B->reg lead-1, counted vmcnt 5/4/0, one
// s_barrier per step; all loads contiguous 1KB dwordx4; ds_reads lane-linear.
__global__ __launch_bounds__(512) void k_gemm(const u16* __restrict__ packA,
    const u16* __restrict__ packB, const float* __restrict__ bias,
    float* __restrict__ outL) {
  const int n  = blockIdx.x >> 4;
  const int mtl = blockIdx.x & 15;
  const int mt = blockIdx.x;            // global 64-row tile index
  const int hw0 = mtl * 64;
  const int t = threadIdx.x;
  const int lane = t & 63, wv = t >> 6;
  const int r15 = lane & 15, hi = lane >> 4;

  __shared__ __align__(16) float smem_f[128 * 68];   // 34.8 KB; A bufs alias first 16 KB
  __shared__ float s_sq[8][64];
  __shared__ float s_rn[64];

  f32x4 acc[4][4];
  #pragma unroll
  for (int a = 0; a < 4; ++a)
    #pragma unroll
    for (int b = 0; b < 4; ++b) acc[a][b] = (f32x4){0.f, 0.f, 0.f, 0.f};

  const u16* asrc = packA + ((size_t)(mt * 64) * 4 + (wv & 3)) * 512 + lane * 8;
  const u16* bbase = packB + (size_t)wv * 131072 + lane * 8;

#define STAGE_A(KT) GLD_LDS16(asrc + (size_t)(KT) * 2048, \
    (char*)smem_f + ((KT) & 3) * 4096 + (wv & 3) * 1024)

  STAGE_A(0);
  STAGE_A(1);
  bf16x8 bc[4], bn[4];
  #pragma unroll
  for (int nf = 0; nf < 4; ++nf) bc[nf] = *(const bf16x8*)(bbase + nf * 512);

  for (int kt = 0; kt < 64; ++kt) {
    if (kt + 2 < 64) STAGE_A(kt + 2);
    if (kt + 1 < 64) {
      #pragma unroll
      for (int nf = 0; nf < 4; ++nf)
        bn[nf] = *(const bf16x8*)(bbase + ((kt + 1) * 4 + nf) * 512);
    }
    __builtin_amdgcn_sched_barrier(0);
    if (kt < 62) {
      asm volatile("s_waitcnt vmcnt(5)" ::: "memory");   // A(kt)+B(kt) retired
    } else if (kt == 62) {
      asm volatile("s_waitcnt vmcnt(4)" ::: "memory");
    } else {
      asm volatile("s_waitcnt vmcnt(0)" ::: "memory");
    }
    __builtin_amdgcn_sched_barrier(0);
    __builtin_amdgcn_s_barrier();                         // A tile kt visible
    __builtin_amdgcn_sched_barrier(0);

    const u16* sA = (const u16*)((const char*)smem_f + (kt & 3) * 4096);
    bf16x8 af[4];
    #pragma unroll
    for (int mf = 0; mf < 4; ++mf)
      af[mf] = *(const bf16x8*)(sA + mf * 512 + lane * 8);
    #pragma unroll
    for (int mf = 0; mf < 4; ++mf)
      #pragma unroll
      for (int nf = 0; nf < 4; ++nf)
        acc[mf][nf] = __builtin_amdgcn_mfma_f32_16x16x32_bf16(af[mf], bc[nf], acc[mf][nf], 0, 0, 0);
    #pragma unroll
    for (int nf = 0; nf < 4; ++nf) bc[nf] = bn[nf];
  }
#undef STAGE_A

  // epilogue: bias, per-row (hw) l2 norm over all 512 f, transposed store
  float badd[4];
  #pragma unroll
  for (int nf = 0; nf < 4; ++nf) badd[nf] = bias[wv * 64 + nf * 16 + r15];
  #pragma unroll
  for (int mf = 0; mf < 4; ++mf)
    #pragma unroll
    for (int nf = 0; nf < 4; ++nf)
      #pragma unroll
      for (int j = 0; j < 4; ++j) acc[mf][nf][j] += badd[nf];

  #pragma unroll
  for (int mf = 0; mf < 4; ++mf)
    #pragma unroll
    for (int j = 0; j < 4; ++j) {
      float s = 0.f;
      #pragma unroll
      for (int nf = 0; nf < 4; ++nf) { float v = acc[mf][nf][j]; s += v * v; }
      s += __shfl_xor(s, 1); s += __shfl_xor(s, 2); s += __shfl_xor(s, 4); s += __shfl_xor(s, 8);
      if ((lane & 15) == 0) s_sq[wv][mf * 16 + hi * 4 + j] = s;
    }
  __syncthreads();
  if (t < 64) {
    float s = 0.f;
    #pragma unroll
    for (int w8 = 0; w8 < 8; ++w8) s += s_sq[w8][t];
    s_rn[t] = 1.0f / fmaxf(sqrtf(s), 1e-12f);
  }
  __syncthreads();

  float* ct = smem_f;   // [128 f-rows][68] fp32
  for (int nf = 0; nf < 4; ++nf) {
    const int fi = wv * 16 + r15;
    #pragma unroll
    for (int mf = 0; mf < 4; ++mf)
      #pragma unroll
      for (int j = 0; j < 4; ++j) {
        int m = mf * 16 + hi * 4 + j;
        ct[fi * 68 + m] = acc[mf][nf][j] * s_rn[m];
      }
    __syncthreads();
    {
      int fr = t >> 2, mq = t & 3;
      int f = (fr >> 4) * 64 + nf * 16 + (fr & 15);
      float* dst = outL + ((size_t)(n * F_ + f)) * HW_ + hw0 + mq * 16;
      const float* srcp = ct + fr * 68 + mq * 16;
      float4 a0 = *(const float4*)(srcp);
      float4 a1 = *(const float4*)(srcp + 4);
      float4 a2 = *(const float4*)(srcp + 8);
      float4 a3 = *(const float4*)(srcp + 12);
      *(float4*)(dst) = a0; *(float4*)(dst + 4) = a1;
      *(float4*)(dst + 8) = a2; *(float4*)(dst + 12) = a3;
    }
    __syncthreads();
  }
}

// ---- K5: GeM finalize: gg = (gbuf/1024)^(1/p) ----
__global__ __launch_bounds__(256) void k_gem_fin(const float* __restrict__ gbuf,
    const float* __restrict__ pvec, float* __restrict__ gg) {
  int i = blockIdx.x * 256 + threadIdx.x;
  float p = pvec[0];
  float m = gbuf[i] * (1.0f / 1024.0f);
  gg[i] = (p == 3.0f) ? cbrtf(m) : powf(m, 1.0f / p);
}

// ---- K6: gproj[n][f] = dot(gg[n], W[f]) + b[f] ----
__global__ __launch_bounds__(256) void k_gproj(const float* __restrict__ w,
    const float* __restrict__ bias, const float* __restrict__ gg,
    float* __restrict__ gproj) {
  const int f = blockIdx.x;
  const int t = threadIdx.x;
  float wreg[8];
  #pragma unroll
  for (int j = 0; j < 8; ++j) wreg[j] = w[(size_t)f * D_ + t + j * 256];
  __shared__ float red[4];
  const int lane = t & 63, wv = t >> 6;
  for (int n = 0; n < N_; ++n) {
    float s = 0.f;
    #pragma unroll
    for (int j = 0; j < 8; ++j) s += wreg[j] * gg[n * D_ + t + j * 256];
    #pragma unroll
    for (int off = 32; off >= 1; off >>= 1) s += __shfl_down(s, off);
    if (lane == 0) red[wv] = s;
    __syncthreads();
    if (t == 0) gproj[n * F_ + f] = red[0] + red[1] + red[2] + red[3] + bias[f];
    __syncthreads();
  }
}

// ---- K7: l2norm g rows -> d_out[0:8192] ----
__global__ __launch_bounds__(512) void k_gnorm(const float* __restrict__ gproj, float* __restrict__ outg) {
  const int n = blockIdx.x;
  const int t = threadIdx.x;
  float v = gproj[n * F_ + t];
  float s = v * v;
  const int lane = t & 63, wv = t >> 6;
  #pragma unroll
  for (int off = 32; off >= 1; off >>= 1) s += __shfl_down(s, off);
  __shared__ float red[8];
  __shared__ float rtot;
  if (lane == 0) red[wv] = s;
  __syncthreads();
  if (t == 0) {
    float a = 0.f;
    #pragma unroll
    for (int i = 0; i < 8; ++i) a += red[i];
    rtot = 1.0f / fmaxf(sqrtf(a), 1e-12f);
  }
  __syncthreads();
  outg[n * F_ + t] = v * rtot;
}

extern "C" void kernel_launch(void* const* d_in, const int* in_sizes, int n_in,
                              void* d_out, int out_size, void* d_ws, size_t ws_size,
                              hipStream_t stream) {
  const float* x  = (const float*)d_in[0];
  const float* pw = (const float*)d_in[1];
  const float* pb = (const float*)d_in[2];
  const float* pv = (const float*)d_in[3];
  float* out = (float*)d_out;

  char* ws = (char*)d_ws;
  float* sumsq = (float*)ws;                                   // 64 KB
  float* gbuf  = (float*)(ws + 65536);                         // 128 KB
  float* gg    = (float*)(ws + 65536 + 131072);                // 128 KB
  float* gproj = (float*)(ws + 65536 + 2 * 131072);            // 32 KB
  u16*   packB = (u16*)(ws + 65536 + 2 * 131072 + 32768);      // 2 MiB
  u16*   packA = (u16*)(ws + 4u * 1024u * 1024u);              // 64 MiB

  k_zero<<<dim3(48), dim3(256), 0, stream>>>(sumsq);           // sumsq + gbuf
  k_sumsq<<<dim3(16, 32), dim3(256), 0, stream>>>(x, sumsq);
  k_wconv<<<dim3(512), dim3(256), 0, stream>>>(pw, packB);
  k_box2<<<dim3(16, 8, 32), dim3(256), 0, stream>>>(x, sumsq, pv, gbuf, packA);
  k_gem_fin<<<dim3(128), dim3(256), 0, stream>>>(gbuf, pv, gg);
  k_gproj<<<dim3(512), dim3(256), 0, stream>>>(pw, pb, gg, gproj);
  k_gnorm<<<dim3(16), dim3(512), 0, stream>>>(gproj, out);
  k_gemm<<<dim3(256), dim3(512), 0, stream>>>(packA, packB, pb, out + N_ * F_);
}